// Round 11
// baseline (270.021 us; speedup 1.0000x reference)
//
#include <hip/hip_runtime.h>
#include <hip/hip_bf16.h>
#include <hip/hip_fp16.h>

#define D_MODEL 1024
#define D_STATE 16
#define D_CONV  4
#define D_INNER 2048
#define DT_RANK 64
#define B_SZ 2
#define SEQ 1024
#define MR (B_SZ*SEQ)   // 2048 rows total

#define BM 128
#define BN 128
#define BK 64   // linear LDS rows (128 B) -> global_load_lds-compatible

typedef float floatx4 __attribute__((ext_vector_type(4)));
typedef short short8 __attribute__((ext_vector_type(8)));
typedef short short4v __attribute__((ext_vector_type(4)));
typedef _Float16 half8 __attribute__((ext_vector_type(8)));

__device__ __forceinline__ float ldf(const __hip_bfloat16* p) { return __bfloat162float(*p); }
__device__ __forceinline__ float ldf(const float* p) { return *p; }
__device__ __forceinline__ float bf2f(short s) {
  union { unsigned u; float f; } v; v.u = ((unsigned)(unsigned short)s) << 16; return v.f;
}
__device__ __forceinline__ short f2bf(float f) {
  __hip_bfloat16 h = __float2bfloat16(f);
  return *reinterpret_cast<short*>(&h);
}

// sum over the 4 lanes of a quad via DPP quad_perm (VALU-only, no LDS pipe)
__device__ __forceinline__ float quad_sum(float y) {
  int r1 = __builtin_amdgcn_mov_dpp(__float_as_int(y), 0xB1, 0xF, 0xF, true); // [1,0,3,2]
  y += __int_as_float(r1);
  int r2 = __builtin_amdgcn_mov_dpp(__float_as_int(y), 0x4E, 0xF, 0xF, true); // [2,3,0,1]
  y += __int_as_float(r2);
  return y;
}

// async global->LDS, 16 B per lane. LDS dest = wave-uniform base + lane*16.
__device__ __forceinline__ void gload_lds16(const void* g, void* l) {
  __builtin_amdgcn_global_load_lds(
      (const __attribute__((address_space(1))) unsigned int*)g,
      (__attribute__((address_space(3))) unsigned int*)l, 16, 0, 0);
}

// ---------- fused prep: x cast (float4->short4) + 4 weight transposes ----------
// 1D grid 8512: [0,2048) x-cast; [2048,6144) W_in^T; [6144,6336) W_x^T;
// [6336,6464) W_dt^T; [6464,8512) W_out^T. Branch is block-uniform.
__global__ __launch_bounds__(256) void prep_kernel(
    const float* __restrict__ x,     __hip_bfloat16* __restrict__ xb,
    const float* __restrict__ W_in,  __hip_bfloat16* __restrict__ WinT,
    const float* __restrict__ W_x,   __hip_bfloat16* __restrict__ WxT,
    const float* __restrict__ W_dt,  __hip_bfloat16* __restrict__ WdtT,
    const float* __restrict__ W_out, __hip_bfloat16* __restrict__ WoutT)
{
  __shared__ float t[32][33];
  int id = blockIdx.x;
  if (id < 2048) {                         // x cast: exactly 524288 float4s
    int i = id * 256 + threadIdx.x;
    floatx4 v = ((const floatx4*)x)[i];
    short4v s;
#pragma unroll
    for (int j = 0; j < 4; ++j) s[j] = f2bf(v[j]);
    ((short4v*)xb)[i] = s;
    return;
  }
  id -= 2048;
  const float* in; __hip_bfloat16* outp; int R, C, bx, by;
  if (id < 4096)        { in = W_in;  outp = WinT;  R = 1024; C = 4096; bx = (id & 127) * 32; by = (id >> 7) * 32; }
  else if (id < 4288)   { id -= 4096; in = W_x;   outp = WxT;  R = 2048; C = 96;   bx = (id % 3) * 32;  by = (id / 3) * 32; }
  else if (id < 4416)   { id -= 4288; in = W_dt;  outp = WdtT; R = 64;   C = 2048; bx = (id & 63) * 32; by = (id >> 6) * 32; }
  else                  { id -= 4416; in = W_out; outp = WoutT;R = 2048; C = 1024; bx = (id & 31) * 32; by = (id >> 5) * 32; }
  const int xx = threadIdx.x & 31;
  const int y4 = (threadIdx.x >> 5) * 4;
#pragma unroll
  for (int i = 0; i < 4; ++i)
    t[y4 + i][xx] = in[(size_t)(by + y4 + i) * C + bx + xx];
  __syncthreads();
#pragma unroll
  for (int i = 0; i < 4; ++i)
    outp[(size_t)(bx + y4 + i) * R + by + xx] = __float2bfloat16(t[xx][y4 + i]);
}

// ---------- MFMA GEMM: C[M,N] = A[M,K] * Bt[N,K]^T ----------
// Staging: global_load_lds dwordx4, linear [BM][BK] LDS (no padding).
// SWZ: bijective XCD-chunked blockIdx remap (requires nwg2d % 8 == 0) -- each
// XCD gets a compact n-major region so its L2 keeps the B-panel resident.
// EPI 0: fp32 store into per-z split-K partial (C + z*M*ldc) -- NO atomics;
// EPI 4: bf16 split store (col<D_INNER -> C, else -> C2);
// EPI 5: fp16 TRANSPOSED softplus store, packed 8B: lane owns 4 consecutive
//        rows of deltaT[col][.] -> one short4v store (guaranteed coalescing).
template <int EPI, bool SWZ = false>
__global__ __launch_bounds__(256) void mfma_gemm(
    const __hip_bfloat16* __restrict__ A, int lda,
    const __hip_bfloat16* __restrict__ Bt, int ldb,
    const float* __restrict__ bias,
    void* __restrict__ C, void* __restrict__ C2, int ldc,
    int M, int N, int Kc)
{
  __shared__ __hip_bfloat16 sA[BM][BK];
  __shared__ __hip_bfloat16 sB[BN][BK];
  const int tid = threadIdx.x;
  const int lane = tid & 63;
  const int wave = tid >> 6;
  const int wm = (wave & 1) * 64;
  const int wn = (wave >> 1) * 64;
  const int tm = lane & 15;
  const int quad = lane >> 4;

  int bx = blockIdx.x, by = blockIdx.y;
  if (SWZ) {
    const int nwg = gridDim.x * gridDim.y;   // per-z 2D grid; must be %8==0
    const int b = bx + gridDim.x * by;       // HW dispatch order (x fastest)
    const int cpx = nwg >> 3;
    const int t = (b & 7) * cpx + (b >> 3);  // XCD k owns t in [k*cpx,(k+1)*cpx)
    by = t % gridDim.y;                      // n-major region decode
    bx = t / gridDim.y;
  }
  const int m0 = by * BM;
  const int n0 = bx * BN;
  const int kbeg = blockIdx.z * Kc;

  const int sr = lane >> 3;          // 0..7
  const int sc = (lane & 7) * 8;     // 0..56

  floatx4 acc[4][4];
#pragma unroll
  for (int i = 0; i < 4; ++i)
#pragma unroll
    for (int j = 0; j < 4; ++j) acc[i][j] = (floatx4){0.f, 0.f, 0.f, 0.f};

  for (int k0 = kbeg; k0 < kbeg + Kc; k0 += BK) {
#pragma unroll
    for (int i = 0; i < 4; ++i) {
      const int blk = i * 4 + wave;        // 0..15 (8-row block of the tile)
      const int r = blk * 8 + sr;          // 0..127
      gload_lds16(&A[(size_t)(m0 + r) * lda + k0 + sc], &sA[blk * 8][0]);
      // N<BN (G3): over-read is benign -- rows 96..127 read the adjacent
      // mapped WdtT region; garbage feeds only cols>=N (discarded in epilogue)
      gload_lds16(&Bt[(size_t)(n0 + r) * ldb + k0 + sc], &sB[blk * 8][0]);
    }
    __syncthreads();
#pragma unroll
    for (int kk = 0; kk < BK; kk += 32) {
      short8 af[4], bfr[4];
#pragma unroll
      for (int i = 0; i < 4; ++i)
        af[i] = *(const short8*)&sA[wm + i * 16 + tm][kk + quad * 8];
#pragma unroll
      for (int j = 0; j < 4; ++j)
        bfr[j] = *(const short8*)&sB[wn + j * 16 + tm][kk + quad * 8];
#pragma unroll
      for (int i = 0; i < 4; ++i)
#pragma unroll
        for (int j = 0; j < 4; ++j)
          acc[i][j] = __builtin_amdgcn_mfma_f32_16x16x32_bf16(
              af[i], bfr[j], acc[i][j], 0, 0, 0);
    }
    __syncthreads();
  }

  // epilogue: C/D layout col=lane&15, row=quad*4+reg
  const size_t zoff = (size_t)blockIdx.z * M * ldc;
#pragma unroll
  for (int i = 0; i < 4; ++i) {
#pragma unroll
    for (int j = 0; j < 4; ++j) {
      int col = n0 + wn + j * 16 + tm;
      if (col >= N) continue;
      int row = m0 + wm + i * 16 + quad * 4;
      if (EPI == 5) {      // packed transposed softplus: 4 consecutive rows
        short4v hb;
#pragma unroll
        for (int r = 0; r < 4; ++r) {
          float xv = acc[i][j][r] + bias[col];
          float sp = (xv > 15.f) ? xv : log1pf(__expf(xv));
          __half hh = __float2half(sp);
          hb[r] = *reinterpret_cast<short*>(&hh);
        }
        *(short4v*)&((__half*)C)[(size_t)col * MR + row] = hb;   // 8B aligned
      } else {
#pragma unroll
        for (int r = 0; r < 4; ++r) {
          float v = acc[i][j][r];
          size_t off = (size_t)(row + r) * ldc + col;
          if (EPI == 0) {
            ((float*)C)[zoff + off] = v;
          } else {  // EPI 4
            if (col < D_INNER)
              ((__hip_bfloat16*)C)[(size_t)(row + r) * D_INNER + col] = __float2bfloat16(v);
            else
              ((__hip_bfloat16*)C2)[(size_t)(row + r) * D_INNER + (col - D_INNER)] = __float2bfloat16(v);
          }
        }
      }
    }
  }
}

// ---------- split-K reduce for G3 (8 slices) + fused bf16 cast ----------
__global__ __launch_bounds__(256) void reduce3_kernel(
    const float* __restrict__ p, float* __restrict__ xdbl,
    __hip_bfloat16* __restrict__ xdblb)
{
  int i = blockIdx.x * 256 + threadIdx.x;     // float4 index over MR*96/4 = 49152
  floatx4 s = ((const floatx4*)p)[i];
#pragma unroll
  for (int z = 1; z < 8; ++z)
    s += ((const floatx4*)(p + (size_t)z * MR * 96))[i];
  ((floatx4*)xdbl)[i] = s;
  short4v b;
#pragma unroll
  for (int j = 0; j < 4; ++j) b[j] = f2bf(s[j]);
  ((short4v*)xdblb)[i] = b;
}

// ---------- split-K reduce for G6 (4 contiguous slices) ----------
__global__ __launch_bounds__(256) void reduce4_kernel(
    const float* __restrict__ p, float* __restrict__ out)
{
  int i = blockIdx.x * 256 + threadIdx.x;     // float4 index over MR*1024/4 = 524288
  floatx4 s = ((const floatx4*)p)[i];
#pragma unroll
  for (int z = 1; z < 4; ++z)
    s += ((const floatx4*)(p + (size_t)z * MR * D_MODEL))[i];
  ((floatx4*)out)[i] = s;
}

// ---------- depthwise causal conv + bias + SiLU, vectorized, dual-layout ----------
__global__ __launch_bounds__(256) void conv_silu_T_kernel(
    const __hip_bfloat16* __restrict__ xe,    // [MR, D_INNER]
    const float* __restrict__ cw,
    const float* __restrict__ cb,
    __hip_bfloat16* __restrict__ xcb,         // [MR, D_INNER]
    __hip_bfloat16* __restrict__ xcT)         // [D_INNER, MR]
{
  __shared__ float t[64][33];    // [channel in tile][row in tile]
  const int tid = threadIdx.x;
  const int row0 = blockIdx.x * 32;        // along MR (32 | 1024: no batch crossing)
  const int c0 = blockIdx.y * 64;          // along D_INNER

  {
    const int r = tid >> 3;                // row in tile
    const int cbase = c0 + (tid & 7) * 8;  // first of 8 channels
    const int row = row0 + r;
    const int l = row & (SEQ - 1);
    floatx4 w[8];
    float bias[8];
#pragma unroll
    for (int j = 0; j < 8; ++j) {
      w[j] = *(const floatx4*)&cw[(cbase + j) * D_CONV];
      bias[j] = cb[cbase + j];
    }
    const __hip_bfloat16* p = &xe[(size_t)row * D_INNER + cbase];
    short8 x3 = *(const short8*)p;
    short8 x2 = (l >= 1) ? *(const short8*)(p - D_INNER) : (short8){0,0,0,0,0,0,0,0};
    short8 x1 = (l >= 2) ? *(const short8*)(p - 2 * D_INNER) : (short8){0,0,0,0,0,0,0,0};
    short8 x0 = (l >= 3) ? *(const short8*)(p - 3 * D_INNER) : (short8){0,0,0,0,0,0,0,0};
    short8 outv;
#pragma unroll
    for (int j = 0; j < 8; ++j) {
      float acc = bias[j];
      acc += bf2f(x0[j]) * w[j][0];
      acc += bf2f(x1[j]) * w[j][1];
      acc += bf2f(x2[j]) * w[j][2];
      acc += bf2f(x3[j]) * w[j][3];
      float s = acc / (1.f + __expf(-acc));
      outv[j] = f2bf(s);
      t[(tid & 7) * 8 + j][r] = s;
    }
    *(short8*)&xcb[(size_t)row * D_INNER + cbase] = outv;
  }
  __syncthreads();
  {
    const int c = tid >> 2;                // channel in tile
    const int rq = (tid & 3) * 8;          // first of 8 rows
    short8 outv;
#pragma unroll
    for (int i = 0; i < 8; ++i) outv[i] = f2bf(t[c][rq + i]);
    *(short8*)&xcT[(size_t)(c0 + c) * MR + row0 + rq] = outv;
  }
}

// ---------- chunked parallel SSM scan: n-quad + 4-chain d-chunk ----------
// Round-10 structure with ONE isolated change: DC 2->4 (halves cross-block
// B/C L2 re-read, the measured scan bottleneck; DC 1->2 was 52.5->47.3us).
// UNCLAMPED __launch_bounds__(256): r5's DC=4 failure was the (256,4) clamp
// forcing 64 VGPR -> 260MB scratch spill, NOT the DC itself. Register audit
// ~115 live -> expect 130-170 alloc, 3 waves/SIMD, no spill.
// REVERT TRIGGERS (pre-committed): scan FETCH > 12 MB or WRITE > 10 MB
// (spill), scan >= 50us, or any non-scan kernel > 50us in top-5 (r9
// co-compilation perturbation signature) -> byte-exact r10 revert.
__global__ __launch_bounds__(256) void scan_kernel(
    const __half* __restrict__ deltaT,          // [D_INNER, MR]
    const __hip_bfloat16* __restrict__ xcT,     // [D_INNER, MR]
    const float* __restrict__ xdbl,             // [MR, 96]  (B at +64, C at +80)
    const float* __restrict__ A_log,            // [2048,16]
    const float* __restrict__ Dp,               // [2048]
    __hip_bfloat16* __restrict__ yT)            // [D_INNER, MR]
{
  __shared__ float s_ap[4][64][17];   // [dc][seg][n]
  __shared__ float s_bc[4][64][17];
  const int tid = threadIdx.x;
  const int nq  = tid & 3;             // n-quad: owns n = 4nq..4nq+3
  const int seg = tid >> 2;            // 0..63, 16 steps each
  const int b   = blockIdx.x >> 9;            // 512 blocks per batch element
  const int d0  = (blockIdx.x & 511) * 4;     // first of 4 chains

  float a_c[4][4];
  float Dv[4];
  size_t cb[4];
#pragma unroll
  for (int dc = 0; dc < 4; ++dc) {
    floatx4 al = *(const floatx4*)&A_log[(d0 + dc) * D_STATE + nq * 4];
#pragma unroll
    for (int e = 0; e < 4; ++e) a_c[dc][e] = -__expf(al[e]);
    Dv[dc] = Dp[d0 + dc];
    cb[dc] = (size_t)(d0 + dc) * MR + b * SEQ + seg * 16;
  }
  const int rbase = b * SEQ + seg * 16;        // first row of this lane's segment

  // ---- Pass 1: per-segment affine composite for 4 chains x 4 n ----
  float ap[4][4], bc[4][4];
#pragma unroll
  for (int dc = 0; dc < 4; ++dc)
#pragma unroll
    for (int e = 0; e < 4; ++e) { ap[dc][e] = 1.f; bc[dc][e] = 0.f; }
#pragma unroll
  for (int c8 = 0; c8 < 2; ++c8) {
    half8 dv8[4]; short8 xc8[4];
#pragma unroll
    for (int dc = 0; dc < 4; ++dc) {
      dv8[dc] = *(const half8*)&deltaT[cb[dc] + c8 * 8];
      xc8[dc] = *(const short8*)&xcT[cb[dc] + c8 * 8];
    }
#pragma unroll
    for (int j = 0; j < 8; ++j) {
      floatx4 Bq = *(const floatx4*)&xdbl[(size_t)(rbase + c8 * 8 + j) * 96 + DT_RANK + nq * 4];
#pragma unroll
      for (int dc = 0; dc < 4; ++dc) {
        const float dv = (float)dv8[dc][j];
        const float t  = dv * bf2f(xc8[dc][j]);
#pragma unroll
        for (int e = 0; e < 4; ++e) {
          float a = __expf(dv * a_c[dc][e]);
          ap[dc][e] *= a;
          bc[dc][e] = a * bc[dc][e] + t * Bq[e];
        }
      }
    }
  }
#pragma unroll
  for (int dc = 0; dc < 4; ++dc)
#pragma unroll
    for (int e = 0; e < 4; ++e) {
      s_ap[dc][seg][nq * 4 + e] = ap[dc][e];
      s_bc[dc][seg][nq * 4 + e] = bc[dc][e];
    }
  __syncthreads();

  // ---- Inter-segment exclusive scan (64 threads: dc = t>>4, n = t&15) ----
  if (tid < 64) {
    const int dc = tid >> 4, n = tid & 15;
    float h = 0.f;
    for (int s = 0; s < 64; ++s) {
      float a_ = s_ap[dc][s][n];
      float b_ = s_bc[dc][s][n];
      s_ap[dc][s][n] = h;              // overwrite with entry state h0
      h = a_ * h + b_;
    }
  }
  __syncthreads();

  // ---- Pass 2: rescan with entry state; quad-DPP n-reduction ----
  float h[4][4];
#pragma unroll
  for (int dc = 0; dc < 4; ++dc)
#pragma unroll
    for (int e = 0; e < 4; ++e) h[dc][e] = s_ap[dc][seg][nq * 4 + e];
#pragma unroll
  for (int c8 = 0; c8 < 2; ++c8) {
    half8 dv8[4]; short8 xc8[4];
#pragma unroll
    for (int dc = 0; dc < 4; ++dc) {
      dv8[dc] = *(const half8*)&deltaT[cb[dc] + c8 * 8];
      xc8[dc] = *(const short8*)&xcT[cb[dc] + c8 * 8];
    }
    short8 ybuf[4];
#pragma unroll
    for (int j = 0; j < 8; ++j) {
      const float* rp = &xdbl[(size_t)(rbase + c8 * 8 + j) * 96 + DT_RANK + nq * 4];
      floatx4 Bq = *(const floatx4*)rp;
      floatx4 Cq = *(const floatx4*)(rp + D_STATE);
#pragma unroll
      for (int dc = 0; dc < 4; ++dc) {
        const float dv  = (float)dv8[dc][j];
        const float xcv = bf2f(xc8[dc][j]);
        const float t   = dv * xcv;
        float y = 0.f;
#pragma unroll
        for (int e = 0; e < 4; ++e) {
          float a = __expf(dv * a_c[dc][e]);
          h[dc][e] = a * h[dc][e] + t * Bq[e];
          y += h[dc][e] * Cq[e];
        }
        y = quad_sum(y);               // sum over the 4 lanes of the quad
        ybuf[dc][j] = f2bf(y + xcv * Dv[dc]);
      }
    }
    if (nq == 0) {
#pragma unroll
      for (int dc = 0; dc < 4; ++dc)
        *(short8*)&yT[cb[dc] + c8 * 8] = ybuf[dc];
    }
  }
}

// ---------- gate: ygb[row][d] = yT[d][row] * silu(z[row][d]), vectorized ----------
__global__ __launch_bounds__(256) void gate_kernel(
    const __hip_bfloat16* __restrict__ yT,   // [D_INNER, MR]
    const __hip_bfloat16* __restrict__ z,    // [MR, D_INNER]
    __hip_bfloat16* __restrict__ ygb)        // [MR, D_INNER]
{
  __shared__ float t[64][33];   // [d in tile][row in tile]
  const int tid = threadIdx.x;
  const int bx = blockIdx.x * 32;   // along MR
  const int by = blockIdx.y * 64;   // along D_INNER
  {
    const int c = tid >> 2;           // d in tile
    const int rq = (tid & 3) * 8;     // first of 8 rows
    short8 yv = *(const short8*)&yT[(size_t)(by + c) * MR + bx + rq];
#pragma unroll
    for (int i = 0; i < 8; ++i) t[c][rq + i] = bf2f(yv[i]);
  }
  __syncthreads();
  {
    const int r = tid >> 3;               // row in tile
    const int dbase = (tid & 7) * 8;      // first of 8 d
    const int row = bx + r;
    short8 zv = *(const short8*)&z[(size_t)row * D_INNER + by + dbase];
    short8 outv;
#pragma unroll
    for (int j = 0; j < 8; ++j) {
      float zf = bf2f(zv[j]);
      float yf = t[dbase + j][r];
      outv[j] = f2bf(yf * (zf / (1.f + __expf(-zf))));
    }
    *(short8*)&ygb[(size_t)row * D_INNER + by + dbase] = outv;
  }
}

extern "C" void kernel_launch(void* const* d_in, const int* in_sizes, int n_in,
                              void* d_out, int out_size, void* d_ws, size_t ws_size,
                              hipStream_t stream)
{
  const float* x     = (const float*)d_in[0];
  const float* W_in  = (const float*)d_in[1];
  const float* cw    = (const float*)d_in[2];
  const float* cb    = (const float*)d_in[3];
  const float* W_x   = (const float*)d_in[4];
  const float* W_dt  = (const float*)d_in[5];
  const float* b_dt  = (const float*)d_in[6];
  const float* A_log = (const float*)d_in[7];
  const float* Dp    = (const float*)d_in[8];
  const float* W_out = (const float*)d_in[9];
  float* out = (float*)d_out;

  // Workspace layout, 44.625 MiB total (< 45.125 MiB previously verified).
  // Region timeline (stream-ordered, producer always retires before reuse):
  //   R0 [ 0, 8)  WinT (prep->G1) -> xcb (conv->G3) -> yT (scan->gate) -> p6.z0
  //   R1 [ 8,16)  xe (G1->conv) -> p3 [8,14) (G3->red3) -> deltaT (G4->scan) -> p6.z1
  //   R2 [16,24)  z (G1->gate) -> p6.z2
  //   R3 [24,32)  xdbl f32 [24,24.75) + xdblb bf16 [24.75,25.125) (red3->scan/G4) -> p6.z3
  //   R4 [32,40)  xb [32,36) (prep->G1) -> xcT (conv->scan) -> ygb (gate->G6)
  //   R5 [40,44)  WoutT (prep->G6)
  //   R6 [44,44.625) WxT [44,44.375) + WdtT [44.375,44.625)
  //   (p6.z0..z3 CONTIGUOUS at [0,32) -> uniform-stride reduce4)
  const size_t MiB = 1 << 20;
  char* wsb = (char*)d_ws;
  __hip_bfloat16* WinT   = (__hip_bfloat16*)(wsb);                     // R0
  __hip_bfloat16* xcb    = (__hip_bfloat16*)(wsb);                     // R0
  __hip_bfloat16* yT     = (__hip_bfloat16*)(wsb);                     // R0
  float*          p6     = (float*)(wsb);                              // [0,32)
  __hip_bfloat16* xe     = (__hip_bfloat16*)(wsb + 8 * MiB);           // R1
  float*          p3     = (float*)(wsb + 8 * MiB);                    // R1 [8,14)
  __half*         deltaT = (__half*)(wsb + 8 * MiB);                   // R1
  __hip_bfloat16* z      = (__hip_bfloat16*)(wsb + 16 * MiB);          // R2
  float*          xdbl   = (float*)(wsb + 24 * MiB);                   // R3
  __hip_bfloat16* xdblb  = (__hip_bfloat16*)(wsb + 24 * MiB + 768 * 1024);
  __hip_bfloat16* xb     = (__hip_bfloat16*)(wsb + 32 * MiB);          // R4 lo
  __hip_bfloat16* xcT    = (__hip_bfloat16*)(wsb + 32 * MiB);          // R4
  __hip_bfloat16* ygb    = (__hip_bfloat16*)(wsb + 32 * MiB);          // R4
  __hip_bfloat16* WoutT  = (__hip_bfloat16*)(wsb + 40 * MiB);          // R5
  __hip_bfloat16* WxT    = (__hip_bfloat16*)(wsb + 44 * MiB);          // R6
  __hip_bfloat16* WdtT   = (__hip_bfloat16*)(wsb + 44 * MiB + 384 * 1024);

  dim3 blk(256);

  // prep: x cast + 4 weight transposes, ONE launch (8512 blocks)
  prep_kernel<<<8512, blk, 0, stream>>>(x, xb, W_in, WinT, W_x, WxT, W_dt, WdtT, W_out, WoutT);

  // 1. [xe|z] = x @ W_in   (M=2048, N=4096, K=1024), bf16 split store, XCD swizzle
  mfma_gemm<4, true><<<dim3(4096 / BN, MR / BM, 1), blk, 0, stream>>>(
      xb, D_MODEL, WinT, D_MODEL, nullptr, xe, z, D_INNER, MR, 2 * D_INNER, D_MODEL);

  // 2. conv + silu -> xcb (row-major) AND xcT (d-major), one pass (vectorized)
  conv_silu_T_kernel<<<dim3(MR / 32, D_INNER / 64), blk, 0, stream>>>(xe, cw, cb, xcb, xcT);

  // 3. xdbl partials = xc @ W_x   (M=2048, N=96, K=2048), split-K=8, NO atomics
  mfma_gemm<0><<<dim3(1, MR / BM, 8), blk, 0, stream>>>(
      xcb, D_INNER, WxT, D_INNER, nullptr, p3, nullptr, 96, MR, 96, D_INNER / 8);
  reduce3_kernel<<<(MR * 96 / 4) / 256, blk, 0, stream>>>(p3, xdbl, xdblb);

  // 4. deltaT = softplus(xdbl[:, :64] @ W_dt + b_dt)^T   (fp16, packed 8B stores)
  mfma_gemm<5><<<dim3(D_INNER / BN, MR / BM, 1), blk, 0, stream>>>(
      xdblb, 96, WdtT, DT_RANK, b_dt, deltaT, nullptr, 0, MR, D_INNER, DT_RANK);

  // 5. chunked parallel SSM scan (n-quad, 4-chain d-chunk, unclamped) -> yT
  scan_kernel<<<(B_SZ * D_INNER) / 4, blk, 0, stream>>>(deltaT, xcT, xdbl, A_log, Dp, yT);

  // 5b. gate: ygb = yT^T * silu(z) (vectorized)
  gate_kernel<<<dim3(MR / 32, D_INNER / 64), blk, 0, stream>>>(yT, z, ygb);

  // 6. out partials = yg @ W_out  (M=2048, N=1024, K=2048), split-K=4, XCD swizzle
  mfma_gemm<0, true><<<dim3(D_MODEL / BN, MR / BM, 4), blk, 0, stream>>>(
      ygb, D_INNER, WoutT, D_INNER, nullptr, p6, nullptr, D_MODEL, MR, D_MODEL, D_INNER / 4);
  reduce4_kernel<<<(MR * D_MODEL / 4) / 256, blk, 0, stream>>>(p6, out);
}

// Round 12
// 254.580 us; speedup vs baseline: 1.0606x; 1.0606x over previous
//
#include <hip/hip_runtime.h>
#include <hip/hip_bf16.h>
#include <hip/hip_fp16.h>

#define D_MODEL 1024
#define D_STATE 16
#define D_CONV  4
#define D_INNER 2048
#define DT_RANK 64
#define B_SZ 2
#define SEQ 1024
#define MR (B_SZ*SEQ)   // 2048 rows total

#define BM 128
#define BN 128
#define BK 64   // linear LDS rows (128 B) -> global_load_lds-compatible

typedef float floatx4 __attribute__((ext_vector_type(4)));
typedef short short8 __attribute__((ext_vector_type(8)));
typedef short short4v __attribute__((ext_vector_type(4)));
typedef _Float16 half8 __attribute__((ext_vector_type(8)));

__device__ __forceinline__ float ldf(const __hip_bfloat16* p) { return __bfloat162float(*p); }
__device__ __forceinline__ float ldf(const float* p) { return *p; }
__device__ __forceinline__ float bf2f(short s) {
  union { unsigned u; float f; } v; v.u = ((unsigned)(unsigned short)s) << 16; return v.f;
}
__device__ __forceinline__ short f2bf(float f) {
  __hip_bfloat16 h = __float2bfloat16(f);
  return *reinterpret_cast<short*>(&h);
}

// sum over the 4 lanes of a quad via DPP quad_perm (VALU-only, no LDS pipe)
__device__ __forceinline__ float quad_sum(float y) {
  int r1 = __builtin_amdgcn_mov_dpp(__float_as_int(y), 0xB1, 0xF, 0xF, true); // [1,0,3,2]
  y += __int_as_float(r1);
  int r2 = __builtin_amdgcn_mov_dpp(__float_as_int(y), 0x4E, 0xF, 0xF, true); // [2,3,0,1]
  y += __int_as_float(r2);
  return y;
}

// async global->LDS, 16 B per lane. LDS dest = wave-uniform base + lane*16.
__device__ __forceinline__ void gload_lds16(const void* g, void* l) {
  __builtin_amdgcn_global_load_lds(
      (const __attribute__((address_space(1))) unsigned int*)g,
      (__attribute__((address_space(3))) unsigned int*)l, 16, 0, 0);
}

// ---------- fused prep: x cast (float4->short4) + 4 weight transposes ----------
// 1D grid 8512: [0,2048) x-cast; [2048,6144) W_in^T; [6144,6336) W_x^T;
// [6336,6464) W_dt^T; [6464,8512) W_out^T. Branch is block-uniform.
__global__ __launch_bounds__(256) void prep_kernel(
    const float* __restrict__ x,     __hip_bfloat16* __restrict__ xb,
    const float* __restrict__ W_in,  __hip_bfloat16* __restrict__ WinT,
    const float* __restrict__ W_x,   __hip_bfloat16* __restrict__ WxT,
    const float* __restrict__ W_dt,  __hip_bfloat16* __restrict__ WdtT,
    const float* __restrict__ W_out, __hip_bfloat16* __restrict__ WoutT)
{
  __shared__ float t[32][33];
  int id = blockIdx.x;
  if (id < 2048) {                         // x cast: exactly 524288 float4s
    int i = id * 256 + threadIdx.x;
    floatx4 v = ((const floatx4*)x)[i];
    short4v s;
#pragma unroll
    for (int j = 0; j < 4; ++j) s[j] = f2bf(v[j]);
    ((short4v*)xb)[i] = s;
    return;
  }
  id -= 2048;
  const float* in; __hip_bfloat16* outp; int R, C, bx, by;
  if (id < 4096)        { in = W_in;  outp = WinT;  R = 1024; C = 4096; bx = (id & 127) * 32; by = (id >> 7) * 32; }
  else if (id < 4288)   { id -= 4096; in = W_x;   outp = WxT;  R = 2048; C = 96;   bx = (id % 3) * 32;  by = (id / 3) * 32; }
  else if (id < 4416)   { id -= 4288; in = W_dt;  outp = WdtT; R = 64;   C = 2048; bx = (id & 63) * 32; by = (id >> 6) * 32; }
  else                  { id -= 4416; in = W_out; outp = WoutT;R = 2048; C = 1024; bx = (id & 31) * 32; by = (id >> 5) * 32; }
  const int xx = threadIdx.x & 31;
  const int y4 = (threadIdx.x >> 5) * 4;
#pragma unroll
  for (int i = 0; i < 4; ++i)
    t[y4 + i][xx] = in[(size_t)(by + y4 + i) * C + bx + xx];
  __syncthreads();
#pragma unroll
  for (int i = 0; i < 4; ++i)
    outp[(size_t)(bx + y4 + i) * R + by + xx] = __float2bfloat16(t[xx][y4 + i]);
}

// ---------- MFMA GEMM: C[M,N] = A[M,K] * Bt[N,K]^T ----------
// Staging: global_load_lds dwordx4, linear [BM][BK] LDS (no padding).
// SWZ: bijective XCD-chunked blockIdx remap (requires nwg2d % 8 == 0) -- each
// XCD gets a compact n-major region so its L2 keeps the B-panel resident.
// EPI 0: fp32 store into per-z split-K partial (C + z*M*ldc) -- NO atomics;
// EPI 4: bf16 split store (col<D_INNER -> C, else -> C2);
// EPI 5: fp16 TRANSPOSED softplus store, packed 8B: lane owns 4 consecutive
//        rows of deltaT[col][.] -> one short4v store (guaranteed coalescing).
template <int EPI, bool SWZ = false>
__global__ __launch_bounds__(256) void mfma_gemm(
    const __hip_bfloat16* __restrict__ A, int lda,
    const __hip_bfloat16* __restrict__ Bt, int ldb,
    const float* __restrict__ bias,
    void* __restrict__ C, void* __restrict__ C2, int ldc,
    int M, int N, int Kc)
{
  __shared__ __hip_bfloat16 sA[BM][BK];
  __shared__ __hip_bfloat16 sB[BN][BK];
  const int tid = threadIdx.x;
  const int lane = tid & 63;
  const int wave = tid >> 6;
  const int wm = (wave & 1) * 64;
  const int wn = (wave >> 1) * 64;
  const int tm = lane & 15;
  const int quad = lane >> 4;

  int bx = blockIdx.x, by = blockIdx.y;
  if (SWZ) {
    const int nwg = gridDim.x * gridDim.y;   // per-z 2D grid; must be %8==0
    const int b = bx + gridDim.x * by;       // HW dispatch order (x fastest)
    const int cpx = nwg >> 3;
    const int t = (b & 7) * cpx + (b >> 3);  // XCD k owns t in [k*cpx,(k+1)*cpx)
    by = t % gridDim.y;                      // n-major region decode
    bx = t / gridDim.y;
  }
  const int m0 = by * BM;
  const int n0 = bx * BN;
  const int kbeg = blockIdx.z * Kc;

  const int sr = lane >> 3;          // 0..7
  const int sc = (lane & 7) * 8;     // 0..56

  floatx4 acc[4][4];
#pragma unroll
  for (int i = 0; i < 4; ++i)
#pragma unroll
    for (int j = 0; j < 4; ++j) acc[i][j] = (floatx4){0.f, 0.f, 0.f, 0.f};

  for (int k0 = kbeg; k0 < kbeg + Kc; k0 += BK) {
#pragma unroll
    for (int i = 0; i < 4; ++i) {
      const int blk = i * 4 + wave;        // 0..15 (8-row block of the tile)
      const int r = blk * 8 + sr;          // 0..127
      gload_lds16(&A[(size_t)(m0 + r) * lda + k0 + sc], &sA[blk * 8][0]);
      // N<BN (G3): over-read is benign -- rows 96..127 read the adjacent
      // mapped WdtT region; garbage feeds only cols>=N (discarded in epilogue)
      gload_lds16(&Bt[(size_t)(n0 + r) * ldb + k0 + sc], &sB[blk * 8][0]);
    }
    __syncthreads();
#pragma unroll
    for (int kk = 0; kk < BK; kk += 32) {
      short8 af[4], bfr[4];
#pragma unroll
      for (int i = 0; i < 4; ++i)
        af[i] = *(const short8*)&sA[wm + i * 16 + tm][kk + quad * 8];
#pragma unroll
      for (int j = 0; j < 4; ++j)
        bfr[j] = *(const short8*)&sB[wn + j * 16 + tm][kk + quad * 8];
#pragma unroll
      for (int i = 0; i < 4; ++i)
#pragma unroll
        for (int j = 0; j < 4; ++j)
          acc[i][j] = __builtin_amdgcn_mfma_f32_16x16x32_bf16(
              af[i], bfr[j], acc[i][j], 0, 0, 0);
    }
    __syncthreads();
  }

  // epilogue: C/D layout col=lane&15, row=quad*4+reg
  const size_t zoff = (size_t)blockIdx.z * M * ldc;
#pragma unroll
  for (int i = 0; i < 4; ++i) {
#pragma unroll
    for (int j = 0; j < 4; ++j) {
      int col = n0 + wn + j * 16 + tm;
      if (col >= N) continue;
      int row = m0 + wm + i * 16 + quad * 4;
      if (EPI == 5) {      // packed transposed softplus: 4 consecutive rows
        short4v hb;
#pragma unroll
        for (int r = 0; r < 4; ++r) {
          float xv = acc[i][j][r] + bias[col];
          float sp = (xv > 15.f) ? xv : log1pf(__expf(xv));
          __half hh = __float2half(sp);
          hb[r] = *reinterpret_cast<short*>(&hh);
        }
        *(short4v*)&((__half*)C)[(size_t)col * MR + row] = hb;   // 8B aligned
      } else {
#pragma unroll
        for (int r = 0; r < 4; ++r) {
          float v = acc[i][j][r];
          size_t off = (size_t)(row + r) * ldc + col;
          if (EPI == 0) {
            ((float*)C)[zoff + off] = v;
          } else {  // EPI 4
            if (col < D_INNER)
              ((__hip_bfloat16*)C)[(size_t)(row + r) * D_INNER + col] = __float2bfloat16(v);
            else
              ((__hip_bfloat16*)C2)[(size_t)(row + r) * D_INNER + (col - D_INNER)] = __float2bfloat16(v);
          }
        }
      }
    }
  }
}

// ---------- split-K reduce for G3 (8 slices) + fused bf16 cast ----------
__global__ __launch_bounds__(256) void reduce3_kernel(
    const float* __restrict__ p, float* __restrict__ xdbl,
    __hip_bfloat16* __restrict__ xdblb)
{
  int i = blockIdx.x * 256 + threadIdx.x;     // float4 index over MR*96/4 = 49152
  floatx4 s = ((const floatx4*)p)[i];
#pragma unroll
  for (int z = 1; z < 8; ++z)
    s += ((const floatx4*)(p + (size_t)z * MR * 96))[i];
  ((floatx4*)xdbl)[i] = s;
  short4v b;
#pragma unroll
  for (int j = 0; j < 4; ++j) b[j] = f2bf(s[j]);
  ((short4v*)xdblb)[i] = b;
}

// ---------- split-K reduce for G6 (4 contiguous slices) ----------
__global__ __launch_bounds__(256) void reduce4_kernel(
    const float* __restrict__ p, float* __restrict__ out)
{
  int i = blockIdx.x * 256 + threadIdx.x;     // float4 index over MR*1024/4 = 524288
  floatx4 s = ((const floatx4*)p)[i];
#pragma unroll
  for (int z = 1; z < 4; ++z)
    s += ((const floatx4*)(p + (size_t)z * MR * D_MODEL))[i];
  ((floatx4*)out)[i] = s;
}

// ---------- depthwise causal conv + bias + SiLU, vectorized, dual-layout ----------
__global__ __launch_bounds__(256) void conv_silu_T_kernel(
    const __hip_bfloat16* __restrict__ xe,    // [MR, D_INNER]
    const float* __restrict__ cw,
    const float* __restrict__ cb,
    __hip_bfloat16* __restrict__ xcb,         // [MR, D_INNER]
    __hip_bfloat16* __restrict__ xcT)         // [D_INNER, MR]
{
  __shared__ float t[64][33];    // [channel in tile][row in tile]
  const int tid = threadIdx.x;
  const int row0 = blockIdx.x * 32;        // along MR (32 | 1024: no batch crossing)
  const int c0 = blockIdx.y * 64;          // along D_INNER

  {
    const int r = tid >> 3;                // row in tile
    const int cbase = c0 + (tid & 7) * 8;  // first of 8 channels
    const int row = row0 + r;
    const int l = row & (SEQ - 1);
    floatx4 w[8];
    float bias[8];
#pragma unroll
    for (int j = 0; j < 8; ++j) {
      w[j] = *(const floatx4*)&cw[(cbase + j) * D_CONV];
      bias[j] = cb[cbase + j];
    }
    const __hip_bfloat16* p = &xe[(size_t)row * D_INNER + cbase];
    short8 x3 = *(const short8*)p;
    short8 x2 = (l >= 1) ? *(const short8*)(p - D_INNER) : (short8){0,0,0,0,0,0,0,0};
    short8 x1 = (l >= 2) ? *(const short8*)(p - 2 * D_INNER) : (short8){0,0,0,0,0,0,0,0};
    short8 x0 = (l >= 3) ? *(const short8*)(p - 3 * D_INNER) : (short8){0,0,0,0,0,0,0,0};
    short8 outv;
#pragma unroll
    for (int j = 0; j < 8; ++j) {
      float acc = bias[j];
      acc += bf2f(x0[j]) * w[j][0];
      acc += bf2f(x1[j]) * w[j][1];
      acc += bf2f(x2[j]) * w[j][2];
      acc += bf2f(x3[j]) * w[j][3];
      float s = acc / (1.f + __expf(-acc));
      outv[j] = f2bf(s);
      t[(tid & 7) * 8 + j][r] = s;
    }
    *(short8*)&xcb[(size_t)row * D_INNER + cbase] = outv;
  }
  __syncthreads();
  {
    const int c = tid >> 2;                // channel in tile
    const int rq = (tid & 3) * 8;          // first of 8 rows
    short8 outv;
#pragma unroll
    for (int i = 0; i < 8; ++i) outv[i] = f2bf(t[c][rq + i]);
    *(short8*)&xcT[(size_t)(c0 + c) * MR + row0 + rq] = outv;
  }
}

// ---------- chunked parallel SSM scan: n-quad + 2-chain d-chunk ----------
// FINAL verified structure (47.3us, VGPR 104, no spill). The DC axis is fully
// measured: DC1=52.5, DC2=47.3, DC4-unclamped=56.2 (VGPR 180 -> 2 waves/SIMD
// bucket). VGPR occupancy buckets (waves/CU halve at 64/128/256, m69) make
// DC=2 the bucket optimum: working set can't fit under 64 VGPR, and >128
// halves latency hiding. Do NOT add a __launch_bounds__ min-waves arg
// ((256,4)@DC4 r5 and (256,5)@DC2 r7 both spilled catastrophically). The
// r9 KS+exp2f+u32 bundle regressed an UNCHANGED mfma_gemm (co-compilation
// perturbation, rule #19) -- do not reintroduce.
__global__ __launch_bounds__(256) void scan_kernel(
    const __half* __restrict__ deltaT,          // [D_INNER, MR]
    const __hip_bfloat16* __restrict__ xcT,     // [D_INNER, MR]
    const float* __restrict__ xdbl,             // [MR, 96]  (B at +64, C at +80)
    const float* __restrict__ A_log,            // [2048,16]
    const float* __restrict__ Dp,               // [2048]
    __hip_bfloat16* __restrict__ yT)            // [D_INNER, MR]
{
  __shared__ float s_ap[2][64][17];   // [dc][seg][n]
  __shared__ float s_bc[2][64][17];
  const int tid = threadIdx.x;
  const int nq  = tid & 3;             // n-quad: owns n = 4nq..4nq+3
  const int seg = tid >> 2;            // 0..63, 16 steps each
  const int b   = blockIdx.x >> 10;           // 1024 blocks per batch element
  const int d0  = (blockIdx.x & 1023) * 2;    // first of 2 chains

  float a_c[2][4];
  float Dv[2];
  size_t cb[2];
#pragma unroll
  for (int dc = 0; dc < 2; ++dc) {
    floatx4 al = *(const floatx4*)&A_log[(d0 + dc) * D_STATE + nq * 4];
#pragma unroll
    for (int e = 0; e < 4; ++e) a_c[dc][e] = -__expf(al[e]);
    Dv[dc] = Dp[d0 + dc];
    cb[dc] = (size_t)(d0 + dc) * MR + b * SEQ + seg * 16;
  }
  const int rbase = b * SEQ + seg * 16;        // first row of this lane's segment

  // ---- Pass 1: per-segment affine composite for 2 chains x 4 n ----
  float ap[2][4], bc[2][4];
#pragma unroll
  for (int dc = 0; dc < 2; ++dc)
#pragma unroll
    for (int e = 0; e < 4; ++e) { ap[dc][e] = 1.f; bc[dc][e] = 0.f; }
#pragma unroll
  for (int c8 = 0; c8 < 2; ++c8) {
    half8 dv8[2]; short8 xc8[2];
#pragma unroll
    for (int dc = 0; dc < 2; ++dc) {
      dv8[dc] = *(const half8*)&deltaT[cb[dc] + c8 * 8];
      xc8[dc] = *(const short8*)&xcT[cb[dc] + c8 * 8];
    }
#pragma unroll
    for (int j = 0; j < 8; ++j) {
      floatx4 Bq = *(const floatx4*)&xdbl[(size_t)(rbase + c8 * 8 + j) * 96 + DT_RANK + nq * 4];
#pragma unroll
      for (int dc = 0; dc < 2; ++dc) {
        const float dv = (float)dv8[dc][j];
        const float t  = dv * bf2f(xc8[dc][j]);
#pragma unroll
        for (int e = 0; e < 4; ++e) {
          float a = __expf(dv * a_c[dc][e]);
          ap[dc][e] *= a;
          bc[dc][e] = a * bc[dc][e] + t * Bq[e];
        }
      }
    }
  }
#pragma unroll
  for (int dc = 0; dc < 2; ++dc)
#pragma unroll
    for (int e = 0; e < 4; ++e) {
      s_ap[dc][seg][nq * 4 + e] = ap[dc][e];
      s_bc[dc][seg][nq * 4 + e] = bc[dc][e];
    }
  __syncthreads();

  // ---- Inter-segment exclusive scan (32 threads: dc = t>>4, n = t&15) ----
  if (tid < 32) {
    const int dc = tid >> 4, n = tid & 15;
    float h = 0.f;
    for (int s = 0; s < 64; ++s) {
      float a_ = s_ap[dc][s][n];
      float b_ = s_bc[dc][s][n];
      s_ap[dc][s][n] = h;              // overwrite with entry state h0
      h = a_ * h + b_;
    }
  }
  __syncthreads();

  // ---- Pass 2: rescan with entry state; quad-DPP n-reduction ----
  float h[2][4];
#pragma unroll
  for (int dc = 0; dc < 2; ++dc)
#pragma unroll
    for (int e = 0; e < 4; ++e) h[dc][e] = s_ap[dc][seg][nq * 4 + e];
#pragma unroll
  for (int c8 = 0; c8 < 2; ++c8) {
    half8 dv8[2]; short8 xc8[2];
#pragma unroll
    for (int dc = 0; dc < 2; ++dc) {
      dv8[dc] = *(const half8*)&deltaT[cb[dc] + c8 * 8];
      xc8[dc] = *(const short8*)&xcT[cb[dc] + c8 * 8];
    }
    short8 ybuf[2];
#pragma unroll
    for (int j = 0; j < 8; ++j) {
      const float* rp = &xdbl[(size_t)(rbase + c8 * 8 + j) * 96 + DT_RANK + nq * 4];
      floatx4 Bq = *(const floatx4*)rp;
      floatx4 Cq = *(const floatx4*)(rp + D_STATE);
#pragma unroll
      for (int dc = 0; dc < 2; ++dc) {
        const float dv  = (float)dv8[dc][j];
        const float xcv = bf2f(xc8[dc][j]);
        const float t   = dv * xcv;
        float y = 0.f;
#pragma unroll
        for (int e = 0; e < 4; ++e) {
          float a = __expf(dv * a_c[dc][e]);
          h[dc][e] = a * h[dc][e] + t * Bq[e];
          y += h[dc][e] * Cq[e];
        }
        y = quad_sum(y);               // sum over the 4 lanes of the quad
        ybuf[dc][j] = f2bf(y + xcv * Dv[dc]);
      }
    }
    if (nq == 0) {
#pragma unroll
      for (int dc = 0; dc < 2; ++dc)
        *(short8*)&yT[cb[dc] + c8 * 8] = ybuf[dc];
    }
  }
}

// ---------- gate: ygb[row][d] = yT[d][row] * silu(z[row][d]), vectorized ----------
__global__ __launch_bounds__(256) void gate_kernel(
    const __hip_bfloat16* __restrict__ yT,   // [D_INNER, MR]
    const __hip_bfloat16* __restrict__ z,    // [MR, D_INNER]
    __hip_bfloat16* __restrict__ ygb)        // [MR, D_INNER]
{
  __shared__ float t[64][33];   // [d in tile][row in tile]
  const int tid = threadIdx.x;
  const int bx = blockIdx.x * 32;   // along MR
  const int by = blockIdx.y * 64;   // along D_INNER
  {
    const int c = tid >> 2;           // d in tile
    const int rq = (tid & 3) * 8;     // first of 8 rows
    short8 yv = *(const short8*)&yT[(size_t)(by + c) * MR + bx + rq];
#pragma unroll
    for (int i = 0; i < 8; ++i) t[c][rq + i] = bf2f(yv[i]);
  }
  __syncthreads();
  {
    const int r = tid >> 3;               // row in tile
    const int dbase = (tid & 7) * 8;      // first of 8 d
    const int row = bx + r;
    short8 zv = *(const short8*)&z[(size_t)row * D_INNER + by + dbase];
    short8 outv;
#pragma unroll
    for (int j = 0; j < 8; ++j) {
      float zf = bf2f(zv[j]);
      float yf = t[dbase + j][r];
      outv[j] = f2bf(yf * (zf / (1.f + __expf(-zf))));
    }
    *(short8*)&ygb[(size_t)row * D_INNER + by + dbase] = outv;
  }
}

extern "C" void kernel_launch(void* const* d_in, const int* in_sizes, int n_in,
                              void* d_out, int out_size, void* d_ws, size_t ws_size,
                              hipStream_t stream)
{
  const float* x     = (const float*)d_in[0];
  const float* W_in  = (const float*)d_in[1];
  const float* cw    = (const float*)d_in[2];
  const float* cb    = (const float*)d_in[3];
  const float* W_x   = (const float*)d_in[4];
  const float* W_dt  = (const float*)d_in[5];
  const float* b_dt  = (const float*)d_in[6];
  const float* A_log = (const float*)d_in[7];
  const float* Dp    = (const float*)d_in[8];
  const float* W_out = (const float*)d_in[9];
  float* out = (float*)d_out;

  // Workspace layout, 44.625 MiB total (< 45.125 MiB previously verified).
  // Region timeline (stream-ordered, producer always retires before reuse):
  //   R0 [ 0, 8)  WinT (prep->G1) -> xcb (conv->G3) -> yT (scan->gate) -> p6.z0
  //   R1 [ 8,16)  xe (G1->conv) -> p3 [8,14) (G3->red3) -> deltaT (G4->scan) -> p6.z1
  //   R2 [16,24)  z (G1->gate) -> p6.z2
  //   R3 [24,32)  xdbl f32 [24,24.75) + xdblb bf16 [24.75,25.125) (red3->scan/G4) -> p6.z3
  //   R4 [32,40)  xb [32,36) (prep->G1) -> xcT (conv->scan) -> ygb (gate->G6)
  //   R5 [40,44)  WoutT (prep->G6)
  //   R6 [44,44.625) WxT [44,44.375) + WdtT [44.375,44.625)
  //   (p6.z0..z3 CONTIGUOUS at [0,32) -> uniform-stride reduce4)
  const size_t MiB = 1 << 20;
  char* wsb = (char*)d_ws;
  __hip_bfloat16* WinT   = (__hip_bfloat16*)(wsb);                     // R0
  __hip_bfloat16* xcb    = (__hip_bfloat16*)(wsb);                     // R0
  __hip_bfloat16* yT     = (__hip_bfloat16*)(wsb);                     // R0
  float*          p6     = (float*)(wsb);                              // [0,32)
  __hip_bfloat16* xe     = (__hip_bfloat16*)(wsb + 8 * MiB);           // R1
  float*          p3     = (float*)(wsb + 8 * MiB);                    // R1 [8,14)
  __half*         deltaT = (__half*)(wsb + 8 * MiB);                   // R1
  __hip_bfloat16* z      = (__hip_bfloat16*)(wsb + 16 * MiB);          // R2
  float*          xdbl   = (float*)(wsb + 24 * MiB);                   // R3
  __hip_bfloat16* xdblb  = (__hip_bfloat16*)(wsb + 24 * MiB + 768 * 1024);
  __hip_bfloat16* xb     = (__hip_bfloat16*)(wsb + 32 * MiB);          // R4 lo
  __hip_bfloat16* xcT    = (__hip_bfloat16*)(wsb + 32 * MiB);          // R4
  __hip_bfloat16* ygb    = (__hip_bfloat16*)(wsb + 32 * MiB);          // R4
  __hip_bfloat16* WoutT  = (__hip_bfloat16*)(wsb + 40 * MiB);          // R5
  __hip_bfloat16* WxT    = (__hip_bfloat16*)(wsb + 44 * MiB);          // R6
  __hip_bfloat16* WdtT   = (__hip_bfloat16*)(wsb + 44 * MiB + 384 * 1024);

  dim3 blk(256);

  // prep: x cast + 4 weight transposes, ONE launch (8512 blocks)
  prep_kernel<<<8512, blk, 0, stream>>>(x, xb, W_in, WinT, W_x, WxT, W_dt, WdtT, W_out, WoutT);

  // 1. [xe|z] = x @ W_in   (M=2048, N=4096, K=1024), bf16 split store, XCD swizzle
  mfma_gemm<4, true><<<dim3(4096 / BN, MR / BM, 1), blk, 0, stream>>>(
      xb, D_MODEL, WinT, D_MODEL, nullptr, xe, z, D_INNER, MR, 2 * D_INNER, D_MODEL);

  // 2. conv + silu -> xcb (row-major) AND xcT (d-major), one pass (vectorized)
  conv_silu_T_kernel<<<dim3(MR / 32, D_INNER / 64), blk, 0, stream>>>(xe, cw, cb, xcb, xcT);

  // 3. xdbl partials = xc @ W_x   (M=2048, N=96, K=2048), split-K=8, NO atomics
  mfma_gemm<0><<<dim3(1, MR / BM, 8), blk, 0, stream>>>(
      xcb, D_INNER, WxT, D_INNER, nullptr, p3, nullptr, 96, MR, 96, D_INNER / 8);
  reduce3_kernel<<<(MR * 96 / 4) / 256, blk, 0, stream>>>(p3, xdbl, xdblb);

  // 4. deltaT = softplus(xdbl[:, :64] @ W_dt + b_dt)^T   (fp16, packed 8B stores)
  mfma_gemm<5><<<dim3(D_INNER / BN, MR / BM, 1), blk, 0, stream>>>(
      xdblb, 96, WdtT, DT_RANK, b_dt, deltaT, nullptr, 0, MR, D_INNER, DT_RANK);

  // 5. chunked parallel SSM scan (n-quad, 2-chain d-chunk) + D skip -> yT
  scan_kernel<<<(B_SZ * D_INNER) / 2, blk, 0, stream>>>(deltaT, xcT, xdbl, A_log, Dp, yT);

  // 5b. gate: ygb = yT^T * silu(z) (vectorized)
  gate_kernel<<<dim3(MR / 32, D_INNER / 64), blk, 0, stream>>>(yT, z, ygb);

  // 6. out partials = yg @ W_out  (M=2048, N=1024, K=2048), split-K=4, XCD swizzle
  mfma_gemm<0, true><<<dim3(D_MODEL / BN, MR / BM, 4), blk, 0, stream>>>(
      ygb, D_INNER, WoutT, D_INNER, nullptr, p6, nullptr, D_MODEL, MR, D_MODEL, D_INNER / 4);
  reduce4_kernel<<<(MR * D_MODEL / 4) / 256, blk, 0, stream>>>(p6, out);
}